// Round 11
// baseline (150.819 us; speedup 1.0000x reference)
//
#include <hip/hip_runtime.h>

// GraphConvBlock, v11 = v8 + (a) pre-summed child inputs (epilogue writes A_s and
// S_{s+1}=A_s+A_{s-1}; staging reads ONE buffer), (b) chunk t+2 issued right
// after phase-t barrier (2-phase slack), (c) lgkm-only head seal (keeps weight
// prologue async). Inner math/layout/swizzles identical to v8.

typedef __bf16 bf16x8 __attribute__((ext_vector_type(8)));
typedef float f32x4 __attribute__((ext_vector_type(4)));

union U4 { uint4 u; bf16x8 b; };

__device__ inline unsigned pk_bf16(float lo, float hi) {
  unsigned r;
  asm volatile("v_cvt_pk_bf16_f32 %0, %1, %2" : "=v"(r) : "v"(lo), "v"(hi));
  return r;
}

__device__ __forceinline__ void gload16(const unsigned* g, unsigned* l) {
  __builtin_amdgcn_global_load_lds(
      (const __attribute__((address_space(1))) unsigned*)(g),
      (__attribute__((address_space(3))) unsigned*)(l), 16, 0, 0);
}

template <int N>
__device__ __forceinline__ void waitcnt_vm_lgkm() {
  if constexpr (N == 0)
    asm volatile("s_waitcnt vmcnt(0) lgkmcnt(0)" ::: "memory");
  else if constexpr (N == 1)
    asm volatile("s_waitcnt vmcnt(1) lgkmcnt(0)" ::: "memory");
  else
    asm volatile("s_waitcnt vmcnt(2) lgkmcnt(0)" ::: "memory");
}

__device__ __forceinline__ void seal_lgkm_barrier() {
  asm volatile("s_waitcnt lgkmcnt(0)" ::: "memory");
  __builtin_amdgcn_s_barrier();
  __builtin_amdgcn_sched_barrier(0);
}

#define WB_WORDS 479232

// ---------------- fused setup kernel (v8 layout) ------------------------------
// Zeros halos of Aa,Sa,Sb,T; repacks weights; transforms x into T.
__global__ __launch_bounds__(512) void setup_all(
    const float* __restrict__ x, const float* __restrict__ W0,
    const float* __restrict__ Wn, unsigned* __restrict__ Aa,
    unsigned* __restrict__ Sa, unsigned* __restrict__ Sb,
    unsigned* __restrict__ T, unsigned* __restrict__ Wb) {
  __shared__ float xl[2 * 64 * 65];
  const int tid = threadIdx.x;
  const int bid = blockIdx.x;
  const int n = bid & 7;

#pragma unroll
  for (int it = 0; it < 4; ++it) {
    unsigned gid = (unsigned)bid * 512 + tid + it * 131072u;
    if (gid < WB_WORDS) {
      const float* src;
      int CIN, c, r, j;
      if (gid < 36864) {
        src = W0; CIN = 64;
        c = gid >> 11; int w = gid & 2047; r = w >> 5; j = w & 31;
      } else {
        unsigned g2 = gid - 36864;
        int s = g2 / 73728; unsigned r2 = g2 % 73728;
        src = Wn + (size_t)s * 147456; CIN = 128;
        c = r2 >> 12; int w = r2 & 4095; r = w >> 6; j = w & 63;
      }
      int ochalf = c / 9, tap = c % 9;
      int dy = tap / 3, dx = tap % 3;
      int icpair = j ^ ((r & 7) << 2);
      int oc = ochalf * 64 + r;
      size_t base = (((size_t)oc * CIN + 2 * icpair) * 3 + dy) * 3 + dx;
      Wb[gid] = pk_bf16(src[base], src[base + 9]);
    }
  }

  {
    unsigned gid = (unsigned)bid * 512 + tid;
    if (gid < 116480) {
      unsigned* buf; int CW; unsigned u;
      if (gid < 99840) {
        buf = gid < 33280 ? Aa : (gid < 66560 ? Sa : Sb);
        u = gid % 33280; CW = 64;
      } else {
        buf = T; u = gid - 99840; CW = 32;
      }
      int per_n = 65 * CW;
      int nn = u / per_n;
      unsigned v = u % per_n;
      int pix = (v * 4) / CW, cw = (v * 4) % CW;
      int row, col;
      if (pix < 66) { row = 0; col = pix; }
      else if (pix < 132) { row = 65; col = pix - 66; }
      else if (pix < 196) { row = pix - 131; col = 0; }
      else { row = pix - 195; col = 65; }
      *(uint4*)&buf[((((size_t)nn * 66 + row) * 66 + col) * CW) + cw] =
          make_uint4(0, 0, 0, 0);
    }
  }

  {
    int hh = bid >> 3;
    int sub = tid >> 8;
    int t8 = tid & 255;
    int h = hh * 2 + sub;
#pragma unroll
    for (int k = 0; k < 16; ++k) {
      int idx = t8 + k * 256;
      int ic = idx >> 6, w = idx & 63;
      xl[(sub * 64 + w) * 65 + ic] = x[(((size_t)n * 64 + ic) * 64 + h) * 64 + w];
    }
    __syncthreads();
#pragma unroll
    for (int k = 0; k < 8; ++k) {
      int idx = t8 + k * 256;
      int w = idx >> 5, icp = idx & 31;
      unsigned v = pk_bf16(xl[(sub * 64 + w) * 65 + icp * 2],
                           xl[(sub * 64 + w) * 65 + icp * 2 + 1]);
      int wp = w + 1;
      int pos = icp ^ ((wp & 7) << 2);
      T[(((size_t)n * 66 + (h + 1)) * 66 + wp) * 32 + pos] = v;
    }
  }
}

// ---------------- unified conv stage -----------------------------------------
// 512 thr = 8 waves = 4 wr x 2 kh; wave = 64oc x 64pix (row h0+wr) x K/2.
// grid 256 = 2 ochalf x 8 n x 16 hq. Single staged input (pre-summed).
template <int CIN, bool WRITE_S, bool WRITE_A, bool OUTF32>
__global__ __launch_bounds__(512, 2) void conv_stage(
    const unsigned* __restrict__ in0, const unsigned* __restrict__ aprev,
    const unsigned* __restrict__ wb, const float* __restrict__ bias,
    float bmult, unsigned* __restrict__ outA, unsigned* __restrict__ outS,
    float* __restrict__ outF) {
  constexpr int WPP = CIN / 2;
  constexpr int CHW = 64 * WPP;
  constexpr int WL = CHW / 2048;
  constexpr int ROWW = 66 * WPP;
  constexpr int ACTW = 6 * ROWW;
  constexpr int ALDS_W = (ACTW > 16384) ? ACTW : 16384;
  constexpr int R4_U4 = 4 * ROWW / 4, R2_U4 = 2 * ROWW / 4;
  constexpr int AJ4 = (R4_U4 + 511) / 512, LJ = (R2_U4 + 511) / 512;
  constexpr int KCW = CIN / 64;

  __shared__ unsigned Alds[ALDS_W];
  __shared__ unsigned Wlds[3][CHW];

  const int tid = threadIdx.x;
  const int lane = tid & 63;
  const int wav = tid >> 6;
  const int wr = wav >> 1;
  const int kh = wav & 1;
  const int l15 = lane & 15, q = lane >> 4;
  const int bid = blockIdx.x;
  const int n = bid & 7;                // same-n -> same XCD (L2 locality)
  const int ochalf = (bid >> 3) & 1;
  const int h0 = (bid >> 4) * 4;

  const unsigned* wbase = wb + (size_t)ochalf * 9 * CHW;
  const size_t abase = ((size_t)n * 66 + h0) * ROWW;
  const uint4* g0 = (const uint4*)(in0 + abase);

  // rows 4,5 to regs first (committed at tail of phase 0)
  uint4 l0[LJ];
#pragma unroll
  for (int j = 0; j < LJ; ++j) {
    int i = tid + j * 512;
    if (i < R2_U4) l0[j] = g0[R4_U4 + i];
  }
  // weight chunks 0,1 async direct-to-LDS
#pragma unroll
  for (int s = 0; s < WL; ++s)
    gload16(wbase + s * 2048 + tid * 4, &Wlds[0][s * 2048 + wav * 256]);
#pragma unroll
  for (int s = 0; s < WL; ++s)
    gload16(wbase + CHW + s * 2048 + tid * 4, &Wlds[1][s * 2048 + wav * 256]);
  // stage act rows 0..3 (single input, no child-sum)
#pragma unroll
  for (int j = 0; j < AJ4; ++j) {
    int i = tid + j * 512;
    if (i < R4_U4) *(uint4*)&Alds[4 * i] = g0[i];
  }
  seal_lgkm_barrier();  // rows 0..3 sealed; weight loads stay in flight

  f32x4 acc[4][4];
#pragma unroll
  for (int m = 0; m < 4; ++m)
#pragma unroll
    for (int p = 0; p < 4; ++p) acc[m][p] = (f32x4)0.f;

#pragma unroll
  for (int t = 0; t < 9; ++t) {
    if (t < 8) waitcnt_vm_lgkm<WL>();
    else waitcnt_vm_lgkm<0>();
    __builtin_amdgcn_s_barrier();
    __builtin_amdgcn_sched_barrier(0);

    // EARLY prefetch: chunk t+2 into buffer (t+2)%3 == (t-1)%3, whose readers
    // all passed the barrier above -> race-free, and gives 2 phases of slack.
    if (t + 2 < 9) {
#pragma unroll
      for (int s = 0; s < WL; ++s)
        gload16(wbase + (size_t)(t + 2) * CHW + s * 2048 + tid * 4,
                &Wlds[(t + 2) % 3][s * 2048 + wav * 256]);
    }
    __builtin_amdgcn_sched_barrier(0);

    const unsigned* WB = Wlds[t % 3];
    const int dy = t / 3, dx = t % 3;
    const int arow = (wr + dy) * 66;

    __builtin_amdgcn_s_setprio(1);
#pragma unroll
    for (int kc2 = 0; kc2 < KCW; ++kc2) {
      const int kc = kh * KCW + kc2;
      bf16x8 a[4];
#pragma unroll
      for (int m = 0; m < 4; ++m) {
        int r = m * 16 + l15;
        U4 u;
        u.u = *(const uint4*)&WB[r * WPP + ((kc * 16 + q * 4) ^ ((r & 7) << 2))];
        a[m] = u.b;
      }
#pragma unroll
      for (int p = 0; p < 4; ++p) {
        int col = p * 16 + l15 + dx;
        U4 u;
        u.u = *(const uint4*)&Alds[(arow + col) * WPP +
                                   ((kc * 16 + q * 4) ^ ((col & 7) << 2))];
        bf16x8 b = u.b;
#pragma unroll
        for (int m = 0; m < 4; ++m)
          acc[m][p] =
              __builtin_amdgcn_mfma_f32_16x16x32_bf16(a[m], b, acc[m][p], 0, 0, 0);
      }
    }
    __builtin_amdgcn_s_setprio(0);
    __builtin_amdgcn_sched_barrier(0);

    // tail of phase 0: commit act rows 4,5 (first read at t=3; sealed by the
    // t=1 wait's lgkmcnt(0) + barrier).
    if (t == 0) {
#pragma unroll
      for (int j = 0; j < LJ; ++j) {
        int i = tid + j * 512;
        if (i < R2_U4) *(uint4*)&Alds[4 * (R4_U4 + i)] = l0[j];
      }
    }
    __builtin_amdgcn_sched_barrier(0);
  }

  // ---- K-pair reduction through LDS (acts dead) ----
  __syncthreads();
  float* R = (float*)Alds;
  if (kh) {
#pragma unroll
    for (int m = 0; m < 4; ++m)
#pragma unroll
      for (int p = 0; p < 4; ++p)
        *(f32x4*)&R[(wr * 16 + m * 4 + p) * 256 + lane * 4] = acc[m][p];
  }
  __syncthreads();
  if (kh) return;
#pragma unroll
  for (int m = 0; m < 4; ++m)
#pragma unroll
    for (int p = 0; p < 4; ++p)
      acc[m][p] += *(const f32x4*)&R[(wr * 16 + m * 4 + p) * 256 + lane * 4];

  // ---- epilogue (kh==0 waves; wave wr owns row h0+wr) ----
  const int obase = ochalf * 64;
  if (OUTF32) {
#pragma unroll
    for (int m = 0; m < 4; ++m) {
      int oc0 = obase + m * 16 + q * 4;
      float4 bb = *(const float4*)&bias[oc0];
#pragma unroll
      for (int p = 0; p < 4; ++p) {
        int w = p * 16 + l15;
#pragma unroll
        for (int j = 0; j < 4; ++j)
          outF[(((size_t)n * 128 + oc0 + j) * 64 + (h0 + wr)) * 64 + w] =
              acc[m][p][j] + ((const float*)&bb)[j] * bmult;
      }
    }
  } else {
#pragma unroll
    for (int m = 0; m < 4; ++m) {
      int oc0 = obase + m * 16 + q * 4;
      float4 bb = *(const float4*)&bias[oc0];
      int icp0 = oc0 >> 1;
#pragma unroll
      for (int p = 0; p < 4; ++p) {
        int w = p * 16 + l15;
        int wp = w + 1;
        int pos = icp0 ^ ((wp & 7) << 2);
        size_t base = (((size_t)n * 66 + (h0 + 1 + wr)) * 66 + wp) * 64;
        float v0 = acc[m][p][0] + bb.x * bmult;
        float v1 = acc[m][p][1] + bb.y * bmult;
        float v2 = acc[m][p][2] + bb.z * bmult;
        float v3 = acc[m][p][3] + bb.w * bmult;
        if (WRITE_A)
          *(uint2*)&outA[base + pos] = make_uint2(pk_bf16(v0, v1), pk_bf16(v2, v3));
        if (WRITE_S) {
          uint2 ap = *(const uint2*)&aprev[base + pos];
          float s0 = v0 + __builtin_bit_cast(float, ap.x << 16);
          float s1 = v1 + __builtin_bit_cast(float, ap.x & 0xFFFF0000u);
          float s2 = v2 + __builtin_bit_cast(float, ap.y << 16);
          float s3 = v3 + __builtin_bit_cast(float, ap.y & 0xFFFF0000u);
          *(uint2*)&outS[base + pos] = make_uint2(pk_bf16(s0, s1), pk_bf16(s2, s3));
        }
      }
    }
  }
}

// ---------------- launch ------------------------------------------------------
extern "C" void kernel_launch(void* const* d_in, const int* in_sizes, int n_in,
                              void* d_out, int out_size, void* d_ws,
                              size_t ws_size, hipStream_t stream) {
  const float* x = (const float*)d_in[0];
  const float* W0 = (const float*)d_in[1];
  const float* b0 = (const float*)d_in[2];
  const float* Wn = (const float*)d_in[3];
  const float* bn = (const float*)d_in[4];

  const size_t ACTB = (size_t)8 * 66 * 66 * 64;  // words per 128-ch act buffer
  const size_t TW = (size_t)8 * 66 * 66 * 32;
  unsigned* Aa = (unsigned*)d_ws;
  unsigned* Ab = Aa + ACTB;
  unsigned* Sa = Ab + ACTB;
  unsigned* Sb = Sa + ACTB;
  unsigned* T = Sb + ACTB;
  unsigned* Wb = T + TW;

  setup_all<<<256, 512, 0, stream>>>(x, W0, Wn, Aa, Sa, Sb, T, Wb);

  dim3 grid(256), blk(512);
  const unsigned* Wd = Wb + 36864;
  const size_t NW = 73728;
  float* OF = (float*)d_out;

  // stem: T -> A0 (Aa)
  conv_stage<64, false, true, false><<<grid, blk, 0, stream>>>(
      T, nullptr, Wb, b0, 1.f, Aa, nullptr, nullptr);
  // node1 {0}: in A0; A1 -> Ab; S2 = A1 + A0 -> Sa
  conv_stage<128, true, true, false><<<grid, blk, 0, stream>>>(
      Aa, Aa, Wd, bn + 0, 1.f, Ab, Sa, nullptr);
  // node2 {0,1}: in S2; A2 -> Aa (A0 dead); S3 = A2 + A1 -> Sb
  conv_stage<128, true, true, false><<<grid, blk, 0, stream>>>(
      Sa, Ab, Wd + 1 * NW, bn + 128, 2.f, Aa, Sb, nullptr);
  // node3 {1,2}: in S3; A3 -> Ab; S4 = A3 + A2 -> Sa
  conv_stage<128, true, true, false><<<grid, blk, 0, stream>>>(
      Sb, Aa, Wd + 2 * NW, bn + 256, 2.f, Ab, Sa, nullptr);
  // node4 {2,3}: in S4; A4 -> Aa; S5 = A4 + A3 -> Sb
  conv_stage<128, true, true, false><<<grid, blk, 0, stream>>>(
      Sa, Ab, Wd + 3 * NW, bn + 384, 2.f, Aa, Sb, nullptr);
  // node5 {3,4}: in S5; S6 = A5 + A4 -> Sa (A5 itself never needed)
  conv_stage<128, true, false, false><<<grid, blk, 0, stream>>>(
      Sb, Aa, Wd + 4 * NW, bn + 512, 2.f, nullptr, Sa, nullptr);
  // node6 {4,5}: in S6 -> d_out (fp32 NCHW)
  conv_stage<128, false, false, true><<<grid, blk, 0, stream>>>(
      Sa, nullptr, Wd + 5 * NW, bn + 640, 2.f, nullptr, nullptr, OF);

  (void)in_sizes; (void)n_in; (void)out_size; (void)ws_size;
}

// Round 12
// 107.672 us; speedup vs baseline: 1.4007x; 1.4007x over previous
//
#include <hip/hip_runtime.h>

// GraphConvBlock, v12: weights in REGISTERS from global (L1/L2-served),
// no weight LDS, no per-phase barriers.
// - Weight repack: per chunk (och,tap), fragment blocks (m,kc) of 1KB laid out
//   so lane l loads uint4 at frag_base + l*16 -> perfectly coalesced; all 256
//   blocks read the same chunks (L1 hit for 3 of 4 redundant wave reads).
// - Acts: v8's bf16 padded swizzled NHWC global layout, staged once to LDS
//   (single __syncthreads), B-frags via swizzled ds_read_b128 (conflict-free).
// - Wave structure (v8): 512 thr = 8 waves = 4 wr x 2 kh; wave = 64oc x 64pix
//   (row h0+wr) x K/2; f32 LDS pair-reduction; grid 256 = 2 och x 8 n x 16 hq.
// - Phase loop: prefetch next tap's A-frags to regs (dbuf, static idx),
//   8(4) ds_read B, 32(16) MFMA. Compiler auto-inserts counted vmcnt.

typedef __bf16 bf16x8 __attribute__((ext_vector_type(8)));
typedef float f32x4 __attribute__((ext_vector_type(4)));

union U4 { uint4 u; bf16x8 b; };

__device__ inline unsigned pk_bf16(float lo, float hi) {
  unsigned r;
  asm volatile("v_cvt_pk_bf16_f32 %0, %1, %2" : "=v"(r) : "v"(lo), "v"(hi));
  return r;
}

__device__ inline unsigned addpk(unsigned a, unsigned b) {
  float alo = __builtin_bit_cast(float, a << 16);
  float ahi = __builtin_bit_cast(float, a & 0xFFFF0000u);
  float blo = __builtin_bit_cast(float, b << 16);
  float bhi = __builtin_bit_cast(float, b & 0xFFFF0000u);
  return pk_bf16(alo + blo, ahi + bhi);
}

__device__ inline uint4 addpk4(uint4 a, uint4 b) {
  return make_uint4(addpk(a.x, b.x), addpk(a.y, b.y), addpk(a.z, b.z), addpk(a.w, b.w));
}

#define WB_WORDS 479232

// ---------------- fused setup kernel -----------------------------------------
// (a) repack weights into coalesced fragment layout:
//   stem: chunk c=och*9+tap (18 chunks of 2048 words at 0); within chunk:
//     frag f = m*2+kc (8 frags of 256 words); word = f*256 + lane*4 + wq;
//     holds pk(W0(oc=och*64+m*16+(lane&15), ic=2*icp), ic=2*icp+1),
//     icp = kc*16 + (lane>>4)*4 + wq.
//   node s: chunk c2=och*9+tap (18 chunks of 4096 words at 36864+s*73728);
//     frag f = m*4+kc (16 frags of 256 words); same lane mapping, CIN=128.
// (b) zero halo rings; (c) transform x -> bf16 padded swizzled T.
__global__ __launch_bounds__(512) void setup_all(
    const float* __restrict__ x, const float* __restrict__ W0,
    const float* __restrict__ Wn, unsigned* __restrict__ B0,
    unsigned* __restrict__ B1, unsigned* __restrict__ B2,
    unsigned* __restrict__ T, unsigned* __restrict__ Wb) {
  __shared__ float xl[2 * 64 * 65];
  const int tid = threadIdx.x;
  const int bid = blockIdx.x;
  const int n = bid & 7;

#pragma unroll
  for (int it = 0; it < 4; ++it) {
    unsigned gid = (unsigned)bid * 512 + tid + it * 131072u;
    if (gid < WB_WORDS) {
      const float* src;
      int CIN, c, w;
      if (gid < 36864) {
        src = W0; CIN = 64;
        c = gid >> 11; w = gid & 2047;
      } else {
        unsigned g2 = gid - 36864;
        int s = g2 / 73728; unsigned r2 = g2 % 73728;
        src = Wn + (size_t)s * 147456; CIN = 128;
        c = r2 >> 12; w = r2 & 4095;
      }
      int och = c / 9, tap = c % 9;
      int dy = tap / 3, dx = tap % 3;
      int f = w >> 8;                       // frag index
      int nkc = CIN / 32;                   // frags per m (2 or 4)
      int m = f / nkc, kc = f % nkc;
      int r8 = w & 255;
      int lane = r8 >> 2, wq = r8 & 3;
      int oc = och * 64 + m * 16 + (lane & 15);
      int icp = kc * 16 + (lane >> 4) * 4 + wq;
      size_t base = (((size_t)oc * CIN + 2 * icp) * 3 + dy) * 3 + dx;
      Wb[gid] = pk_bf16(src[base], src[base + 9]);
    }
  }

  {
    unsigned gid = (unsigned)bid * 512 + tid;
    if (gid < 116480) {
      unsigned* buf; int CW; unsigned u;
      if (gid < 99840) {
        buf = gid < 33280 ? B0 : (gid < 66560 ? B1 : B2);
        u = gid % 33280; CW = 64;
      } else {
        buf = T; u = gid - 99840; CW = 32;
      }
      int per_n = 65 * CW;
      int nn = u / per_n;
      unsigned v = u % per_n;
      int pix = (v * 4) / CW, cw = (v * 4) % CW;
      int row, col;
      if (pix < 66) { row = 0; col = pix; }
      else if (pix < 132) { row = 65; col = pix - 66; }
      else if (pix < 196) { row = pix - 131; col = 0; }
      else { row = pix - 195; col = 65; }
      *(uint4*)&buf[((((size_t)nn * 66 + row) * 66 + col) * CW) + cw] =
          make_uint4(0, 0, 0, 0);
    }
  }

  {
    int hh = bid >> 3;
    int sub = tid >> 8;
    int t8 = tid & 255;
    int h = hh * 2 + sub;
#pragma unroll
    for (int k = 0; k < 16; ++k) {
      int idx = t8 + k * 256;
      int ic = idx >> 6, w = idx & 63;
      xl[(sub * 64 + w) * 65 + ic] = x[(((size_t)n * 64 + ic) * 64 + h) * 64 + w];
    }
    __syncthreads();
#pragma unroll
    for (int k = 0; k < 8; ++k) {
      int idx = t8 + k * 256;
      int w = idx >> 5, icp = idx & 31;
      unsigned v = pk_bf16(xl[(sub * 64 + w) * 65 + icp * 2],
                           xl[(sub * 64 + w) * 65 + icp * 2 + 1]);
      int wp = w + 1;
      int pos = icp ^ ((wp & 7) << 2);
      T[(((size_t)n * 66 + (h + 1)) * 66 + wp) * 32 + pos] = v;
    }
  }
}

// ---------------- unified conv stage (reg-weights, barrier-free loop) --------
template <int CIN, bool DUAL, bool OUTF32>
__global__ __launch_bounds__(512, 2) void conv_stage(
    const unsigned* __restrict__ in0, const unsigned* __restrict__ in1,
    const unsigned* __restrict__ wb, const float* __restrict__ bias,
    float bmult, void* __restrict__ outp) {
  constexpr int WPP = CIN / 2;          // u32 words per pixel
  constexpr int CHW = 64 * WPP;         // words per weight chunk
  constexpr int CH_U4 = CHW / 4;        // uint4 per chunk
  constexpr int NKC_TOT = WPP / 16;     // kc values total (2 or 4)
  constexpr int KCW = NKC_TOT / 2;      // kc per kh (1 or 2)
  constexpr int ROWW = 66 * WPP;
  constexpr int ACTW = 6 * ROWW;
  constexpr int ALDS_W = (ACTW > 16384) ? ACTW : 16384;
  constexpr int ACT_U4 = ACTW / 4;
  constexpr int AJ = (ACT_U4 + 511) / 512;

  __shared__ unsigned Alds[ALDS_W];

  const int tid = threadIdx.x;
  const int lane = tid & 63;
  const int wav = tid >> 6;
  const int wr = wav >> 1;              // output row 0..3
  const int kh = wav & 1;               // K half
  const int l15 = lane & 15, q = lane >> 4;
  const int bid = blockIdx.x;
  const int n = bid & 7;                // same-n -> same XCD (L2 locality)
  const int ochalf = (bid >> 3) & 1;
  const int h0 = (bid >> 4) * 4;

  // per-wave weight fragment pointer: frag (m, kc=kh*KCW+kc2), lane-coalesced
  const uint4* wg = (const uint4*)(wb + (size_t)ochalf * 9 * CHW);
  // index (uint4): tap*CH_U4 + (m*NKC_TOT + kh*KCW + kc2)*64 + lane

  // ---- stage all 6 act rows (fused child-sum), one barrier ----
  {
    const size_t abase = ((size_t)n * 66 + h0) * ROWW;
    const uint4* g0 = (const uint4*)(in0 + abase);
    const uint4* g1 = (const uint4*)(in1 + abase);
#pragma unroll
    for (int j = 0; j < AJ; ++j) {
      int i = tid + j * 512;
      if (i < ACT_U4) {
        uint4 v = g0[i];
        if (DUAL) v = addpk4(v, g1[i]);
        *(uint4*)&Alds[4 * i] = v;
      }
    }
  }

  // prefetch tap 0 A-frags into regs (overlaps staging stores)
  uint4 wcur[4][KCW], wnxt[4][KCW];
#pragma unroll
  for (int m = 0; m < 4; ++m)
#pragma unroll
    for (int kc2 = 0; kc2 < KCW; ++kc2)
      wcur[m][kc2] = wg[(m * NKC_TOT + kh * KCW + kc2) * 64 + lane];

  __syncthreads();  // acts visible to all waves

  f32x4 acc[4][4];
#pragma unroll
  for (int m = 0; m < 4; ++m)
#pragma unroll
    for (int p = 0; p < 4; ++p) acc[m][p] = (f32x4)0.f;

#pragma unroll
  for (int t = 0; t < 9; ++t) {
    // prefetch next tap's A-frags (compiler emits counted vmcnt before use)
    if (t < 8) {
#pragma unroll
      for (int m = 0; m < 4; ++m)
#pragma unroll
        for (int kc2 = 0; kc2 < KCW; ++kc2)
          wnxt[m][kc2] =
              wg[(t + 1) * CH_U4 + (m * NKC_TOT + kh * KCW + kc2) * 64 + lane];
    }

    const int dy = t / 3, dx = t % 3;
    const int arow = (wr + dy) * 66;

    __builtin_amdgcn_s_setprio(1);
#pragma unroll
    for (int kc2 = 0; kc2 < KCW; ++kc2) {
      const int kc = kh * KCW + kc2;
      bf16x8 a[4];
#pragma unroll
      for (int m = 0; m < 4; ++m) {
        U4 u; u.u = wcur[m][kc2]; a[m] = u.b;
      }
#pragma unroll
      for (int p = 0; p < 4; ++p) {
        int col = p * 16 + l15 + dx;
        U4 u;
        u.u = *(const uint4*)&Alds[(arow + col) * WPP +
                                   ((kc * 16 + q * 4) ^ ((col & 7) << 2))];
        bf16x8 b = u.b;
#pragma unroll
        for (int m = 0; m < 4; ++m)
          acc[m][p] =
              __builtin_amdgcn_mfma_f32_16x16x32_bf16(a[m], b, acc[m][p], 0, 0, 0);
      }
    }
    __builtin_amdgcn_s_setprio(0);

    // static swap (fully unrolled loop -> stays in registers)
#pragma unroll
    for (int m = 0; m < 4; ++m)
#pragma unroll
      for (int kc2 = 0; kc2 < KCW; ++kc2) wcur[m][kc2] = wnxt[m][kc2];
  }

  // ---- K-pair reduction through LDS (acts dead) ----
  __syncthreads();  // all act reads done before overwrite
  float* R = (float*)Alds;
  if (kh) {
#pragma unroll
    for (int m = 0; m < 4; ++m)
#pragma unroll
      for (int p = 0; p < 4; ++p)
        *(f32x4*)&R[(wr * 16 + m * 4 + p) * 256 + lane * 4] = acc[m][p];
  }
  __syncthreads();
  if (kh) return;
#pragma unroll
  for (int m = 0; m < 4; ++m)
#pragma unroll
    for (int p = 0; p < 4; ++p)
      acc[m][p] += *(const f32x4*)&R[(wr * 16 + m * 4 + p) * 256 + lane * 4];

  // ---- epilogue (kh==0 waves; wave wr owns row h0+wr) ----
  const int obase = ochalf * 64;
  if (OUTF32) {
    float* out = (float*)outp;
#pragma unroll
    for (int m = 0; m < 4; ++m) {
      int oc0 = obase + m * 16 + q * 4;
      float4 bb = *(const float4*)&bias[oc0];
#pragma unroll
      for (int p = 0; p < 4; ++p) {
        int w = p * 16 + l15;
#pragma unroll
        for (int j = 0; j < 4; ++j)
          out[(((size_t)n * 128 + oc0 + j) * 64 + (h0 + wr)) * 64 + w] =
              acc[m][p][j] + ((const float*)&bb)[j] * bmult;
      }
    }
  } else {
    unsigned* out = (unsigned*)outp;
#pragma unroll
    for (int m = 0; m < 4; ++m) {
      int oc0 = obase + m * 16 + q * 4;
      float4 bb = *(const float4*)&bias[oc0];
      int icp0 = oc0 >> 1;
#pragma unroll
      for (int p = 0; p < 4; ++p) {
        int w = p * 16 + l15;
        int wp = w + 1;
        unsigned lo = pk_bf16(acc[m][p][0] + bb.x * bmult, acc[m][p][1] + bb.y * bmult);
        unsigned hi = pk_bf16(acc[m][p][2] + bb.z * bmult, acc[m][p][3] + bb.w * bmult);
        int pos = icp0 ^ ((wp & 7) << 2);
        size_t base = (((size_t)n * 66 + (h0 + 1 + wr)) * 66 + wp) * 64;
        *(uint2*)&out[base + pos] = make_uint2(lo, hi);
      }
    }
  }
}

// ---------------- launch ------------------------------------------------------
extern "C" void kernel_launch(void* const* d_in, const int* in_sizes, int n_in,
                              void* d_out, int out_size, void* d_ws,
                              size_t ws_size, hipStream_t stream) {
  const float* x = (const float*)d_in[0];
  const float* W0 = (const float*)d_in[1];
  const float* b0 = (const float*)d_in[2];
  const float* Wn = (const float*)d_in[3];
  const float* bn = (const float*)d_in[4];

  const size_t ACTB = (size_t)8 * 66 * 66 * 64;
  const size_t TW = (size_t)8 * 66 * 66 * 32;
  unsigned* B0 = (unsigned*)d_ws;
  unsigned* B1 = B0 + ACTB;
  unsigned* B2 = B1 + ACTB;
  unsigned* T = B2 + ACTB;
  unsigned* Wb = T + TW;

  setup_all<<<256, 512, 0, stream>>>(x, W0, Wn, B0, B1, B2, T, Wb);

  dim3 grid(256), blk(512);
  const unsigned* Wnode = Wb + 36864;
  const size_t NW = 73728;

  // stem: T -> B0
  conv_stage<64, false, false><<<grid, blk, 0, stream>>>(T, T, Wb, b0, 1.f, B0);
  // node1 {0}: B0 -> B1
  conv_stage<128, false, false><<<grid, blk, 0, stream>>>(B0, B0, Wnode, bn + 0, 1.f, B1);
  // node2 {0,1}: B0+B1 -> B2
  conv_stage<128, true, false><<<grid, blk, 0, stream>>>(B0, B1, Wnode + 1 * NW, bn + 128, 2.f, B2);
  // node3 {1,2}: B1+B2 -> B0
  conv_stage<128, true, false><<<grid, blk, 0, stream>>>(B1, B2, Wnode + 2 * NW, bn + 256, 2.f, B0);
  // node4 {2,3}: B2+B0 -> B1
  conv_stage<128, true, false><<<grid, blk, 0, stream>>>(B2, B0, Wnode + 3 * NW, bn + 384, 2.f, B1);
  // node5 {3,4}: B0+B1 -> B2
  conv_stage<128, true, false><<<grid, blk, 0, stream>>>(B0, B1, Wnode + 4 * NW, bn + 512, 2.f, B2);
  // node6 {4,5}: B1+B2 -> d_out (fp32 NCHW)
  conv_stage<128, true, true><<<grid, blk, 0, stream>>>(B1, B2, Wnode + 5 * NW, bn + 640, 2.f, d_out);

  (void)in_sizes; (void)n_in; (void)out_size; (void)ws_size;
}